// Round 1
// baseline (1077.582 us; speedup 1.0000x reference)
//
#include <hip/hip_runtime.h>

// Problem constants (fixed by the reference: N = 512*512, E = N*8, grid 512)
#define NN 262144
#define NE 2097152
constexpr int GS = 512;
constexpr int P  = GS * GS;   // == NN

// ---------------------------------------------------------------------------
// CSR build: histogram -> scan -> scatter
// ---------------------------------------------------------------------------
__global__ __launch_bounds__(256) void k_hist(const int4* __restrict__ dst,
                                              int* __restrict__ cnt) {
  int i = blockIdx.x * 256 + threadIdx.x;           // exactly NE/4 threads
  int4 d = dst[i];
  atomicAdd(&cnt[d.x], 1); atomicAdd(&cnt[d.y], 1);
  atomicAdd(&cnt[d.z], 1); atomicAdd(&cnt[d.w], 1);
}

__global__ __launch_bounds__(256) void k_scan1(const int* __restrict__ cnt,
                                               int* __restrict__ bsums) {
  __shared__ int sd[256];
  int t = threadIdx.x;
  int4 v = *(const int4*)&cnt[blockIdx.x * 1024 + t * 4];
  sd[t] = v.x + v.y + v.z + v.w;
  __syncthreads();
  for (int off = 128; off > 0; off >>= 1) {
    if (t < off) sd[t] += sd[t + off];
    __syncthreads();
  }
  if (t == 0) bsums[blockIdx.x] = sd[0];
}

__global__ __launch_bounds__(256) void k_scan2(int* bsums) {
  __shared__ int sd[256];
  int t = threadIdx.x;
  sd[t] = bsums[t];
  __syncthreads();
  for (int off = 1; off < 256; off <<= 1) {
    int v = (t >= off) ? sd[t - off] : 0;
    __syncthreads();
    sd[t] += v;
    __syncthreads();
  }
  bsums[t] = (t == 0) ? 0 : sd[t - 1];              // exclusive
}

__global__ __launch_bounds__(256) void k_scan3(const int* __restrict__ cnt,
                                               const int* __restrict__ bsums,
                                               int* __restrict__ offs,
                                               int* __restrict__ cursor) {
  __shared__ int sd[256];
  int t = threadIdx.x;
  int base = blockIdx.x * 1024 + t * 4;
  int4 v = *(const int4*)&cnt[base];
  sd[t] = v.x + v.y + v.z + v.w;
  __syncthreads();
  for (int off = 1; off < 256; off <<= 1) {
    int q = (t >= off) ? sd[t - off] : 0;
    __syncthreads();
    sd[t] += q;
    __syncthreads();
  }
  int e0 = bsums[blockIdx.x] + ((t == 0) ? 0 : sd[t - 1]);
  int e1 = e0 + v.x, e2 = e1 + v.y, e3 = e2 + v.z;
  int4 o4 = make_int4(e0, e1, e2, e3);
  *(int4*)&offs[base]   = o4;
  *(int4*)&cursor[base] = o4;
  if (blockIdx.x == 0 && t == 0) offs[NN] = NE;
}

__global__ __launch_bounds__(256) void k_dinv(const int* __restrict__ cnt,
                                              float* __restrict__ dinv) {
  int i = blockIdx.x * 256 + threadIdx.x;
  dinv[i] = rsqrtf((float)(cnt[i] + 1));            // +1 self loop; always > 0
}

__global__ __launch_bounds__(256) void k_scatter(const int4* __restrict__ src,
                                                 const int4* __restrict__ dst,
                                                 int* __restrict__ cursor,
                                                 int* __restrict__ ssrc) {
  int i = blockIdx.x * 256 + threadIdx.x;
  int4 s = src[i]; int4 d = dst[i];
  ssrc[atomicAdd(&cursor[d.x], 1)] = s.x;
  ssrc[atomicAdd(&cursor[d.y], 1)] = s.y;
  ssrc[atomicAdd(&cursor[d.z], 1)] = s.z;
  ssrc[atomicAdd(&cursor[d.w], 1)] = s.w;
}

// ---------------------------------------------------------------------------
// GCN compute
// ---------------------------------------------------------------------------
// xagg = A_norm * x  (4 features, thread per node)
__global__ __launch_bounds__(256) void k_agg4(const float4* __restrict__ x,
                                              const float* __restrict__ dinv,
                                              const int* __restrict__ offs,
                                              const int* __restrict__ ssrc,
                                              float4* __restrict__ out) {
  for (int i = blockIdx.x * 256 + threadIdx.x; i < NN; i += gridDim.x * 256) {
    float di = dinv[i];
    float4 a = x[i];
    float sw = di * di;
    float4 acc = make_float4(a.x * sw, a.y * sw, a.z * sw, a.w * sw);
    int k = offs[i], e = offs[i + 1];
    for (; k < e; ++k) {
      int s = ssrc[k];
      float w = dinv[s] * di;
      float4 xs = x[s];
      acc.x += xs.x * w; acc.y += xs.y * w;
      acc.z += xs.z * w; acc.w += xs.w * w;
    }
    out[i] = acc;
  }
}

// out[n][f] = sum_k h[n][k] * W[k][f] (+bias, relu). Wave per node, lane = f.
template <int K, bool RELU>
__global__ __launch_bounds__(256) void k_matmul(const float* __restrict__ h,
                                                const float* __restrict__ W,
                                                const float* __restrict__ bias,
                                                float* __restrict__ out) {
  __shared__ float Wl[K * 64];
  for (int i = threadIdx.x; i < K * 64; i += 256) Wl[i] = W[i];
  __syncthreads();
  int lane = threadIdx.x & 63;
  int wv   = threadIdx.x >> 6;
  float bl = bias ? bias[lane] : 0.f;
  for (int node = blockIdx.x * 4 + wv; node < NN; node += gridDim.x * 4) {
    const float* hr = h + (size_t)node * K;
    float acc = bl;
#pragma unroll
    for (int k = 0; k < K; ++k) acc += hr[k] * Wl[k * 64 + lane];
    out[(size_t)node * 64 + lane] = RELU ? fmaxf(acc, 0.f) : acc;
  }
}

// out = relu(A_norm * h + b)  (64 features, wave per node, lane = feature)
__global__ __launch_bounds__(256) void k_agg64(const float* __restrict__ h,
                                               const float* __restrict__ dinv,
                                               const int* __restrict__ offs,
                                               const int* __restrict__ ssrc,
                                               const float* __restrict__ bias,
                                               float* __restrict__ out) {
  int lane = threadIdx.x & 63;
  int wv   = threadIdx.x >> 6;
  float bl = bias[lane];
  for (int i = blockIdx.x * 4 + wv; i < NN; i += gridDim.x * 4) {
    float di = dinv[i];
    float acc = h[(size_t)i * 64 + lane] * di * di;   // self loop
    int k = offs[i], e = offs[i + 1];
    for (; k + 4 <= e; k += 4) {
      int s0 = ssrc[k], s1 = ssrc[k + 1], s2 = ssrc[k + 2], s3 = ssrc[k + 3];
      float w0 = dinv[s0] * di, w1 = dinv[s1] * di;
      float w2 = dinv[s2] * di, w3 = dinv[s3] * di;
      float v0 = h[(size_t)s0 * 64 + lane], v1 = h[(size_t)s1 * 64 + lane];
      float v2 = h[(size_t)s2 * 64 + lane], v3 = h[(size_t)s3 * 64 + lane];
      acc += v0 * w0; acc += v1 * w1; acc += v2 * w2; acc += v3 * w3;
    }
    for (; k < e; ++k) {
      int s = ssrc[k];
      acc += h[(size_t)s * 64 + lane] * (dinv[s] * di);
    }
    out[(size_t)i * 64 + lane] = fmaxf(acc + bl, 0.f);
  }
}

// channels-last [P][64] -> planar [64][P]
__global__ __launch_bounds__(256) void k_transpose(const float* __restrict__ in,
                                                   float* __restrict__ out) {
  __shared__ float t[64][65];
  int tx = threadIdx.x & 63;
  int ty = threadIdx.x >> 6;
  int base = blockIdx.x * 64;
#pragma unroll
  for (int i = 0; i < 16; ++i) {
    int p = ty + i * 4;
    t[p][tx] = in[(size_t)(base + p) * 64 + tx];
  }
  __syncthreads();
#pragma unroll
  for (int i = 0; i < 16; ++i) {
    int c = ty + i * 4;
    out[(size_t)c * P + base + tx] = t[tx][c];
  }
}

// ---------------------------------------------------------------------------
// Planar 3x3 SAME conv, 2 px/thread, all COUT channels in registers.
// Weights staged to LDS as [c][ky][kx][o], chunks of <=32 input channels.
// ---------------------------------------------------------------------------
template <int CIN, int COUT, bool RELU>
__global__ __launch_bounds__(256) void k_conv(const float* __restrict__ in,
                                              const float* __restrict__ w,
                                              const float* __restrict__ cb,
                                              float* __restrict__ out) {
  constexpr int CCH = (CIN > 32) ? 32 : CIN;
  __shared__ float wl[CCH * 9 * COUT];

  int tx = threadIdx.x;          // 0..63
  int ty = threadIdx.y;          // 0..3
  int tid = ty * 64 + tx;
  int x0 = (blockIdx.x * 64 + tx) * 2;
  int y  = blockIdx.y * 4 + ty;

  float acc0[COUT], acc1[COUT];
#pragma unroll
  for (int o = 0; o < COUT; ++o) { acc0[o] = 0.f; acc1[o] = 0.f; }

  bool xlo = (x0 - 1) >= 0;
  bool xhi = (x0 + 2) <= (GS - 1);
  int dlo = xlo ? -1 : 0;
  int dhi = xhi ? 2 : 0;

  for (int cb0 = 0; cb0 < CIN; cb0 += CCH) {
    __syncthreads();
    for (int idx = tid; idx < CCH * 9 * COUT; idx += 256) {
      int o = idx % COUT; int r = idx / COUT;
      int kx = r % 3; r /= 3; int ky = r % 3; int cl = r / 3;
      wl[idx] = w[(((o * CIN) + cb0 + cl) * 3 + ky) * 3 + kx];
    }
    __syncthreads();

#pragma unroll 1
    for (int cl = 0; cl < CCH; ++cl) {
      int c = cb0 + cl;
      float iv[3][4];
#pragma unroll
      for (int r = 0; r < 3; ++r) {
        int yy = y + r - 1;
        int yc = yy < 0 ? 0 : (yy > GS - 1 ? GS - 1 : yy);
        bool rok = (yy >= 0) && (yy < GS);
        const float* ip = in + (size_t)c * P + (size_t)yc * GS + x0;
        iv[r][0] = (rok && xlo) ? ip[dlo] : 0.f;
        iv[r][1] = rok ? ip[0] : 0.f;
        iv[r][2] = rok ? ip[1] : 0.f;
        iv[r][3] = (rok && xhi) ? ip[dhi] : 0.f;
      }
#pragma unroll
      for (int ky = 0; ky < 3; ++ky)
#pragma unroll
        for (int kx = 0; kx < 3; ++kx) {
          const float* wp = &wl[((cl * 3 + ky) * 3 + kx) * COUT];
          float a = iv[ky][kx], b = iv[ky][kx + 1];
          if constexpr (COUT % 4 == 0) {
#pragma unroll
            for (int o4 = 0; o4 < COUT / 4; ++o4) {
              float4 wv = *(const float4*)&wp[o4 * 4];
              acc0[o4*4+0] += a * wv.x; acc1[o4*4+0] += b * wv.x;
              acc0[o4*4+1] += a * wv.y; acc1[o4*4+1] += b * wv.y;
              acc0[o4*4+2] += a * wv.z; acc1[o4*4+2] += b * wv.z;
              acc0[o4*4+3] += a * wv.w; acc1[o4*4+3] += b * wv.w;
            }
          } else {
#pragma unroll
            for (int o2 = 0; o2 < COUT / 2; ++o2) {
              float2 wv = *(const float2*)&wp[o2 * 2];
              acc0[o2*2+0] += a * wv.x; acc1[o2*2+0] += b * wv.x;
              acc0[o2*2+1] += a * wv.y; acc1[o2*2+1] += b * wv.y;
            }
          }
        }
    }
  }

  size_t obase = (size_t)y * GS + x0;
#pragma unroll
  for (int o = 0; o < COUT; ++o) {
    float v0 = acc0[o] + cb[o];
    float v1 = acc1[o] + cb[o];
    if (RELU) { v0 = fmaxf(v0, 0.f); v1 = fmaxf(v1, 0.f); }
    *(float2*)&out[(size_t)o * P + obase] = make_float2(v0, v1);
  }
}

// ---------------------------------------------------------------------------
extern "C" void kernel_launch(void* const* d_in, const int* in_sizes, int n_in,
                              void* d_out, int out_size, void* d_ws, size_t ws_size,
                              hipStream_t stream) {
  const float* x   = (const float*)d_in[0];
  const int*   esr = (const int*)d_in[1];
  const int*   eds = (const int*)d_in[2];
  const float* W1  = (const float*)d_in[4];
  const float* b1  = (const float*)d_in[5];
  const float* W2  = (const float*)d_in[6];
  const float* b2  = (const float*)d_in[7];
  const float* W3  = (const float*)d_in[8];
  const float* b3  = (const float*)d_in[9];
  const float* cw1 = (const float*)d_in[10];
  const float* cb1 = (const float*)d_in[11];
  const float* cw2 = (const float*)d_in[12];
  const float* cb2 = (const float*)d_in[13];
  const float* cw3 = (const float*)d_in[14];
  const float* cb3 = (const float*)d_in[15];
  const float* cw4 = (const float*)d_in[16];
  const float* cb4 = (const float*)d_in[17];
  float* out = (float*)d_out;

  char* ws = (char*)d_ws;
  const size_t MB = 1 << 20;
  float* hA   = (float*)(ws);                 // 64 MB
  float* hB   = (float*)(ws + 64 * MB);       // 64 MB
  int*   ssrc = (int*)(ws + 128 * MB);        // 8 MB
  float* dinv = (float*)(ws + 136 * MB);      // 1 MB
  int*   cnt  = (int*)(ws + 137 * MB);        // 1 MB
  int*   offs = (int*)(ws + 138 * MB);        // 1 MB + 4 (give 2 MB)
  int*   curs = (int*)(ws + 140 * MB);        // 1 MB
  float* xagg = (float*)(ws + 141 * MB);      // 4 MB
  int*   bsum = (int*)(ws + 145 * MB);        // 1 KB

  // ---- CSR build ----
  hipMemsetAsync(cnt, 0, NN * sizeof(int), stream);
  k_hist<<<NE / 1024, 256, 0, stream>>>((const int4*)eds, cnt);
  k_scan1<<<256, 256, 0, stream>>>(cnt, bsum);
  k_scan2<<<1, 256, 0, stream>>>(bsum);
  k_scan3<<<256, 256, 0, stream>>>(cnt, bsum, offs, curs);
  k_dinv<<<NN / 256, 256, 0, stream>>>(cnt, dinv);
  k_scatter<<<NE / 1024, 256, 0, stream>>>((const int4*)esr, (const int4*)eds,
                                           curs, ssrc);

  // ---- GCN ----
  // layer 1: h1 = relu((A x) W1 + b1)
  k_agg4<<<1024, 256, 0, stream>>>((const float4*)x, dinv, offs, ssrc,
                                   (float4*)xagg);
  k_matmul<4, true><<<2048, 256, 0, stream>>>(xagg, W1, b1, hA);
  // layer 2
  k_matmul<64, false><<<2048, 256, 0, stream>>>(hA, W2, nullptr, hB);
  k_agg64<<<2048, 256, 0, stream>>>(hB, dinv, offs, ssrc, b2, hA);
  // layer 3
  k_matmul<64, false><<<2048, 256, 0, stream>>>(hA, W3, nullptr, hB);
  k_agg64<<<2048, 256, 0, stream>>>(hB, dinv, offs, ssrc, b3, hA);

  // ---- CNN ----
  k_transpose<<<NN / 64, 256, 0, stream>>>(hA, hB);   // [P][64] -> [64][P]
  dim3 cgrid(4, 128), cblk(64, 4);
  k_conv<64, 32, true ><<<cgrid, cblk, 0, stream>>>(hB, cw1, cb1, hA);
  k_conv<32, 16, true ><<<cgrid, cblk, 0, stream>>>(hA, cw2, cb2, hB);
  k_conv<16,  8, true ><<<cgrid, cblk, 0, stream>>>(hB, cw3, cb3, hA);
  k_conv< 8,  6, false><<<cgrid, cblk, 0, stream>>>(hA, cw4, cb4, out);
}

// Round 2
// 978.633 us; speedup vs baseline: 1.1011x; 1.1011x over previous
//
#include <hip/hip_runtime.h>

// Problem constants (fixed by the reference: N = 512*512, E = N*8, grid 512)
#define NN 262144
#define NE 2097152
constexpr int GS = 512;
constexpr int P  = GS * GS;   // == NN

// ---------------------------------------------------------------------------
// CSR build: histogram -> scan -> scatter
// ---------------------------------------------------------------------------
__global__ __launch_bounds__(256) void k_hist(const int4* __restrict__ dst,
                                              int* __restrict__ cnt) {
  int i = blockIdx.x * 256 + threadIdx.x;           // exactly NE/4 threads
  int4 d = dst[i];
  atomicAdd(&cnt[d.x], 1); atomicAdd(&cnt[d.y], 1);
  atomicAdd(&cnt[d.z], 1); atomicAdd(&cnt[d.w], 1);
}

__global__ __launch_bounds__(256) void k_scan1(const int* __restrict__ cnt,
                                               int* __restrict__ bsums) {
  __shared__ int sd[256];
  int t = threadIdx.x;
  int4 v = *(const int4*)&cnt[blockIdx.x * 1024 + t * 4];
  sd[t] = v.x + v.y + v.z + v.w;
  __syncthreads();
  for (int off = 128; off > 0; off >>= 1) {
    if (t < off) sd[t] += sd[t + off];
    __syncthreads();
  }
  if (t == 0) bsums[blockIdx.x] = sd[0];
}

__global__ __launch_bounds__(256) void k_scan2(int* bsums) {
  __shared__ int sd[256];
  int t = threadIdx.x;
  sd[t] = bsums[t];
  __syncthreads();
  for (int off = 1; off < 256; off <<= 1) {
    int v = (t >= off) ? sd[t - off] : 0;
    __syncthreads();
    sd[t] += v;
    __syncthreads();
  }
  bsums[t] = (t == 0) ? 0 : sd[t - 1];              // exclusive
}

__global__ __launch_bounds__(256) void k_scan3(const int* __restrict__ cnt,
                                               const int* __restrict__ bsums,
                                               int* __restrict__ offs,
                                               int* __restrict__ cursor) {
  __shared__ int sd[256];
  int t = threadIdx.x;
  int base = blockIdx.x * 1024 + t * 4;
  int4 v = *(const int4*)&cnt[base];
  sd[t] = v.x + v.y + v.z + v.w;
  __syncthreads();
  for (int off = 1; off < 256; off <<= 1) {
    int q = (t >= off) ? sd[t - off] : 0;
    __syncthreads();
    sd[t] += q;
    __syncthreads();
  }
  int e0 = bsums[blockIdx.x] + ((t == 0) ? 0 : sd[t - 1]);
  int e1 = e0 + v.x, e2 = e1 + v.y, e3 = e2 + v.z;
  int4 o4 = make_int4(e0, e1, e2, e3);
  *(int4*)&offs[base]   = o4;
  *(int4*)&cursor[base] = o4;
  if (blockIdx.x == 0 && t == 0) offs[NN] = NE;
}

__global__ __launch_bounds__(256) void k_dinv(const int* __restrict__ cnt,
                                              float* __restrict__ dinv) {
  int i = blockIdx.x * 256 + threadIdx.x;
  dinv[i] = rsqrtf((float)(cnt[i] + 1));            // +1 self loop; always > 0
}

__global__ __launch_bounds__(256) void k_scatter(const int4* __restrict__ src,
                                                 const int4* __restrict__ dst,
                                                 int* __restrict__ cursor,
                                                 int* __restrict__ ssrc) {
  int i = blockIdx.x * 256 + threadIdx.x;
  int4 s = src[i]; int4 d = dst[i];
  ssrc[atomicAdd(&cursor[d.x], 1)] = s.x;
  ssrc[atomicAdd(&cursor[d.y], 1)] = s.y;
  ssrc[atomicAdd(&cursor[d.z], 1)] = s.z;
  ssrc[atomicAdd(&cursor[d.w], 1)] = s.w;
}

// ---------------------------------------------------------------------------
// GCN compute
// ---------------------------------------------------------------------------
// xagg = A_norm * x  (4 features, thread per node)
__global__ __launch_bounds__(256) void k_agg4(const float4* __restrict__ x,
                                              const float* __restrict__ dinv,
                                              const int* __restrict__ offs,
                                              const int* __restrict__ ssrc,
                                              float4* __restrict__ out) {
  for (int i = blockIdx.x * 256 + threadIdx.x; i < NN; i += gridDim.x * 256) {
    float di = dinv[i];
    float4 a = x[i];
    float sw = di * di;
    float4 acc = make_float4(a.x * sw, a.y * sw, a.z * sw, a.w * sw);
    int k = offs[i], e = offs[i + 1];
    for (; k < e; ++k) {
      int s = ssrc[k];
      float w = dinv[s] * di;
      float4 xs = x[s];
      acc.x += xs.x * w; acc.y += xs.y * w;
      acc.z += xs.z * w; acc.w += xs.w * w;
    }
    out[i] = acc;
  }
}

// out[n][f] = sum_k h[n][k] * W[k][f] (+bias, relu). Wave per node, lane = f.
// Weights per-lane in VGPRs; h row read via SGPR (readfirstlane -> s_load).
template <int K, bool RELU>
__global__ __launch_bounds__(256) void k_matmul(const float* __restrict__ h,
                                                const float* __restrict__ W,
                                                const float* __restrict__ bias,
                                                float* __restrict__ out) {
  int lane = threadIdx.x & 63;
  int wv   = threadIdx.x >> 6;
  float wreg[K];
#pragma unroll
  for (int k = 0; k < K; ++k) wreg[k] = W[k * 64 + lane];
  float bl = bias ? bias[lane] : 0.f;
  for (int node = blockIdx.x * 4 + wv; node < NN; node += gridDim.x * 4) {
    int nu = __builtin_amdgcn_readfirstlane(node);
    const float* hr = h + (size_t)nu * K;
    float acc = bl;
#pragma unroll
    for (int q = 0; q < K / 4; ++q) {
      float4 hv = *(const float4*)(hr + q * 4);
      acc = fmaf(hv.x, wreg[q * 4 + 0], acc);
      acc = fmaf(hv.y, wreg[q * 4 + 1], acc);
      acc = fmaf(hv.z, wreg[q * 4 + 2], acc);
      acc = fmaf(hv.w, wreg[q * 4 + 3], acc);
    }
    out[(size_t)node * 64 + lane] = RELU ? fmaxf(acc, 0.f) : acc;
  }
}

// out = relu(A_norm * h + b)  (64 features, wave per node, lane = feature)
__global__ __launch_bounds__(256) void k_agg64(const float* __restrict__ h,
                                               const float* __restrict__ dinv,
                                               const int* __restrict__ offs,
                                               const int* __restrict__ ssrc,
                                               const float* __restrict__ bias,
                                               float* __restrict__ out) {
  int lane = threadIdx.x & 63;
  int wv   = threadIdx.x >> 6;
  float bl = bias[lane];
  for (int i = blockIdx.x * 4 + wv; i < NN; i += gridDim.x * 4) {
    float di = dinv[i];
    float acc = h[(size_t)i * 64 + lane] * di * di;   // self loop
    int k = offs[i], e = offs[i + 1];
    for (; k + 4 <= e; k += 4) {
      int s0 = ssrc[k], s1 = ssrc[k + 1], s2 = ssrc[k + 2], s3 = ssrc[k + 3];
      float w0 = dinv[s0] * di, w1 = dinv[s1] * di;
      float w2 = dinv[s2] * di, w3 = dinv[s3] * di;
      float v0 = h[(size_t)s0 * 64 + lane], v1 = h[(size_t)s1 * 64 + lane];
      float v2 = h[(size_t)s2 * 64 + lane], v3 = h[(size_t)s3 * 64 + lane];
      acc += v0 * w0; acc += v1 * w1; acc += v2 * w2; acc += v3 * w3;
    }
    for (; k < e; ++k) {
      int s = ssrc[k];
      acc += h[(size_t)s * 64 + lane] * (dinv[s] * di);
    }
    out[(size_t)i * 64 + lane] = fmaxf(acc + bl, 0.f);
  }
}

// channels-last [P][64] -> planar [64][P]
__global__ __launch_bounds__(256) void k_transpose(const float* __restrict__ in,
                                                   float* __restrict__ out) {
  __shared__ float t[64][65];
  int tx = threadIdx.x & 63;
  int ty = threadIdx.x >> 6;
  int base = blockIdx.x * 64;
#pragma unroll
  for (int i = 0; i < 16; ++i) {
    int p = ty + i * 4;
    t[p][tx] = in[(size_t)(base + p) * 64 + tx];
  }
  __syncthreads();
#pragma unroll
  for (int i = 0; i < 16; ++i) {
    int c = ty + i * 4;
    out[(size_t)c * P + base + tx] = t[tx][c];
  }
}

// Repack conv weights OIHW -> [c][tap][o] for uniform (scalar) loads.
template <int CIN, int COUT>
__global__ __launch_bounds__(256) void k_wrep(const float* __restrict__ w,
                                              float* __restrict__ wr) {
  int i = blockIdx.x * 256 + threadIdx.x;
  if (i >= CIN * 9 * COUT) return;
  int o = i % COUT;
  int t = (i / COUT) % 9;
  int c = i / (COUT * 9);
  wr[i] = w[(o * CIN + c) * 9 + t];
}

// ---------------------------------------------------------------------------
// Planar 3x3 SAME conv, 2 px/thread, all COUT channels in registers.
// Weights read wave-uniformly from global (compiler scalarizes to s_load);
// zero LDS -> no LDS-broadcast bottleneck.
// ---------------------------------------------------------------------------
template <int CIN, int COUT, bool RELU>
__global__ __launch_bounds__(256) void k_conv(const float* __restrict__ in,
                                              const float* __restrict__ wrep,
                                              const float* __restrict__ cb,
                                              float* __restrict__ out) {
  int tx = threadIdx.x;          // 0..63
  int ty = threadIdx.y;          // 0..3
  int x0 = (blockIdx.x * 64 + tx) * 2;
  int y  = blockIdx.y * 4 + ty;

  float acc0[COUT], acc1[COUT];
#pragma unroll
  for (int o = 0; o < COUT; ++o) { acc0[o] = 0.f; acc1[o] = 0.f; }

  bool xlo = (x0 - 1) >= 0;
  bool xhi = (x0 + 2) <= (GS - 1);
  int dlo = xlo ? -1 : 0;
  int dhi = xhi ? 2 : 0;

#pragma unroll 1
  for (int c = 0; c < CIN; ++c) {
    float iv[3][4];
#pragma unroll
    for (int r = 0; r < 3; ++r) {
      int yy = y + r - 1;
      int yc = yy < 0 ? 0 : (yy > GS - 1 ? GS - 1 : yy);
      bool rok = (yy >= 0) && (yy < GS);
      const float* ip = in + (size_t)c * P + (size_t)yc * GS + x0;
      iv[r][0] = (rok && xlo) ? ip[dlo] : 0.f;
      iv[r][1] = rok ? ip[0] : 0.f;
      iv[r][2] = rok ? ip[1] : 0.f;
      iv[r][3] = (rok && xhi) ? ip[dhi] : 0.f;
    }
    const float* wc = wrep + c * 9 * COUT;   // wave-uniform -> s_load
#pragma unroll
    for (int t = 0; t < 9; ++t) {
      int ky = t / 3, kx = t % 3;
      float a = iv[ky][kx], b = iv[ky][kx + 1];
#pragma unroll
      for (int o = 0; o < COUT; ++o) {
        float wv = wc[t * COUT + o];
        acc0[o] = fmaf(a, wv, acc0[o]);
        acc1[o] = fmaf(b, wv, acc1[o]);
      }
    }
  }

  size_t obase = (size_t)y * GS + x0;
#pragma unroll
  for (int o = 0; o < COUT; ++o) {
    float v0 = acc0[o] + cb[o];
    float v1 = acc1[o] + cb[o];
    if (RELU) { v0 = fmaxf(v0, 0.f); v1 = fmaxf(v1, 0.f); }
    *(float2*)&out[(size_t)o * P + obase] = make_float2(v0, v1);
  }
}

// ---------------------------------------------------------------------------
extern "C" void kernel_launch(void* const* d_in, const int* in_sizes, int n_in,
                              void* d_out, int out_size, void* d_ws, size_t ws_size,
                              hipStream_t stream) {
  const float* x   = (const float*)d_in[0];
  const int*   esr = (const int*)d_in[1];
  const int*   eds = (const int*)d_in[2];
  const float* W1  = (const float*)d_in[4];
  const float* b1  = (const float*)d_in[5];
  const float* W2  = (const float*)d_in[6];
  const float* b2  = (const float*)d_in[7];
  const float* W3  = (const float*)d_in[8];
  const float* b3  = (const float*)d_in[9];
  const float* cw1 = (const float*)d_in[10];
  const float* cb1 = (const float*)d_in[11];
  const float* cw2 = (const float*)d_in[12];
  const float* cb2 = (const float*)d_in[13];
  const float* cw3 = (const float*)d_in[14];
  const float* cb3 = (const float*)d_in[15];
  const float* cw4 = (const float*)d_in[16];
  const float* cb4 = (const float*)d_in[17];
  float* out = (float*)d_out;

  char* ws = (char*)d_ws;
  const size_t MB = 1 << 20;
  float* hA   = (float*)(ws);                 // 64 MB
  float* hB   = (float*)(ws + 64 * MB);       // 64 MB
  int*   ssrc = (int*)(ws + 128 * MB);        // 8 MB
  float* dinv = (float*)(ws + 136 * MB);      // 1 MB
  int*   cnt  = (int*)(ws + 137 * MB);        // 1 MB
  int*   offs = (int*)(ws + 138 * MB);        // 1 MB + 4 B
  float* wr1  = (float*)(ws + 139 * MB + 4096);  // 72 KB
  float* wr2  = wr1 + 64 * 9 * 32;               // 18 KB
  float* wr3  = wr2 + 32 * 9 * 16;               // 4.5 KB
  float* wr4  = wr3 + 16 * 9 * 8;                // 1.7 KB
  int*   curs = (int*)(ws + 140 * MB);        // 1 MB
  float* xagg = (float*)(ws + 141 * MB);      // 4 MB
  int*   bsum = (int*)(ws + 145 * MB);        // 1 KB

  // ---- CSR build ----
  hipMemsetAsync(cnt, 0, NN * sizeof(int), stream);
  k_hist<<<NE / 1024, 256, 0, stream>>>((const int4*)eds, cnt);
  k_scan1<<<256, 256, 0, stream>>>(cnt, bsum);
  k_scan2<<<1, 256, 0, stream>>>(bsum);
  k_scan3<<<256, 256, 0, stream>>>(cnt, bsum, offs, curs);
  k_dinv<<<NN / 256, 256, 0, stream>>>(cnt, dinv);
  k_scatter<<<NE / 1024, 256, 0, stream>>>((const int4*)esr, (const int4*)eds,
                                           curs, ssrc);

  // ---- conv weight repacks (independent; run early) ----
  k_wrep<64, 32><<<(64 * 9 * 32 + 255) / 256, 256, 0, stream>>>(cw1, wr1);
  k_wrep<32, 16><<<(32 * 9 * 16 + 255) / 256, 256, 0, stream>>>(cw2, wr2);
  k_wrep<16,  8><<<(16 * 9 *  8 + 255) / 256, 256, 0, stream>>>(cw3, wr3);
  k_wrep< 8,  6><<<( 8 * 9 *  6 + 255) / 256, 256, 0, stream>>>(cw4, wr4);

  // ---- GCN ----
  // layer 1: h1 = relu((A x) W1 + b1)
  k_agg4<<<1024, 256, 0, stream>>>((const float4*)x, dinv, offs, ssrc,
                                   (float4*)xagg);
  k_matmul<4, true><<<2048, 256, 0, stream>>>(xagg, W1, b1, hA);
  // layer 2
  k_matmul<64, false><<<2048, 256, 0, stream>>>(hA, W2, nullptr, hB);
  k_agg64<<<2048, 256, 0, stream>>>(hB, dinv, offs, ssrc, b2, hA);
  // layer 3
  k_matmul<64, false><<<2048, 256, 0, stream>>>(hA, W3, nullptr, hB);
  k_agg64<<<2048, 256, 0, stream>>>(hB, dinv, offs, ssrc, b3, hA);

  // ---- CNN ----
  k_transpose<<<NN / 64, 256, 0, stream>>>(hA, hB);   // [P][64] -> [64][P]
  dim3 cgrid(4, 128), cblk(64, 4);
  k_conv<64, 32, true ><<<cgrid, cblk, 0, stream>>>(hB, wr1, cb1, hA);
  k_conv<32, 16, true ><<<cgrid, cblk, 0, stream>>>(hA, wr2, cb2, hB);
  k_conv<16,  8, true ><<<cgrid, cblk, 0, stream>>>(hB, wr3, cb3, hA);
  k_conv< 8,  6, false><<<cgrid, cblk, 0, stream>>>(hA, wr4, cb4, out);
}